// Round 6
// baseline (225.355 us; speedup 1.0000x reference)
//
#include <hip/hip_runtime.h>
#include <math.h>

#define DD 2048   // hidden dim
#define EE 16     // experts
#define RR 16     // lora rank
#define QO 2048   // q out dim
#define VO 512    // v out dim
#define DSPLIT 8  // D splits for A-side grid (32 KB panels -> 4 blocks/CU)
#define DRANGE (DD / DSPLIT)   // 256
#define DC 64     // D-chunk per pipeline stage
#define RDC 256        // router D-chunk
#define DSPL 8         // router D-split (one RDC chunk per block)
#define TW 4           // tokens per WAVE (register budget ~100 VGPR, no spill)
#define TBI (TW * 4)   // 16 tokens per block iteration (4 waves)
#define ABLK 8         // a_kernel grid.y -> 16*8*8 = 1024 blocks = 4/CU, 1 round
#define T2 32          // B-side tokens per tile
#define CGQ (QO / 256) // 8 q column groups
#define CGV (VO / 256) // 2 v column groups

struct Route { int i0, i1; float w0, w1; };

// XOR-swizzled A-panel addressing (dense [DRANGE][16] + quad swizzle).
// Read lanes (s, rp) at d = s+16k hit bank-quads (s&1)<<2 | (rp^((s>>1)&3))
// -> bijective over s&7 -> 2-way conflict (free), no padding (16 KB/panel).
__device__ __forceinline__ int apos(int d, int rq) {
    return d * 16 + ((rq ^ ((d >> 1) & 3)) << 2);
}

// ---------------- K1a: partial fp64 logits over a 256-wide D slice --------
// grid (n/8, DSPL). Block (0,0) also zeroes cnt (consumed only by finalize,
// which is stream-ordered after this kernel).
__global__ __launch_bounds__(256) void logits_kernel(
    const float* __restrict__ h, const float* __restrict__ rw,
    double* __restrict__ lgp, int* __restrict__ cnt, int n)
{
    __shared__ float hs[8 * RDC];       // 8 KB

    if (blockIdx.x == 0 && blockIdx.y == 0 && threadIdx.x < EE)
        cnt[threadIdx.x] = 0;

    int t0 = blockIdx.x * 8;
    int ds = blockIdx.y;
    int d0 = ds * RDC;
    int e  = threadIdx.x >> 4;
    int l  = threadIdx.x & 15;

    // stage h chunk: 8 tokens x 256 d = 512 float4 tasks = 2/thread
    for (int i = threadIdx.x; i < 8 * (RDC / 4); i += 256) {
        int t = i >> 6, dq = (i & 63) * 4;
        float4 v = make_float4(0.f, 0.f, 0.f, 0.f);
        if (t0 + t < n)
            v = *(const float4*)&h[(size_t)(t0 + t) * DD + d0 + dq];
        *(float4*)&hs[t * RDC + dq] = v;
    }
    __syncthreads();

    double acc[8];
#pragma unroll
    for (int t = 0; t < 8; ++t) acc[t] = 0.0;

    const float* rwe = rw + e * DD + d0;
#pragma unroll
    for (int g = 0; g < RDC / 64; ++g) {          // 4 passes
        int d = g * 64 + l * 4;
        float4 r4 = *(const float4*)&rwe[d];
        double rx = r4.x, ry = r4.y, rz = r4.z, rw4 = r4.w;
#pragma unroll
        for (int t = 0; t < 8; ++t) {
            float4 hv = *(const float4*)&hs[t * RDC + d];
            acc[t] += (double)hv.x * rx + (double)hv.y * ry
                    + (double)hv.z * rz + (double)hv.w * rw4;
        }
    }
#pragma unroll
    for (int t = 0; t < 8; ++t) {
#pragma unroll
        for (int off = 8; off; off >>= 1)
            acc[t] += __shfl_down(acc[t], off, 16);
    }
    if (l == 0) {
#pragma unroll
        for (int t = 0; t < 8; ++t) {
            int tok = t0 + t;
            if (tok < n)
                lgp[((size_t)tok * DSPL + ds) * EE + e] = acc[t];
        }
    }
}

// ---------------- K1b: finalize router, 16 lanes per token ----------------
// Lane l = expert. fp64 ds-sum in fixed order (bit-identical to serial).
// Butterfly argmax with lowest-index tie-break == serial scan semantics.
__global__ __launch_bounds__(256) void finalize_kernel(
    const double* __restrict__ lgp, Route* __restrict__ route,
    unsigned short* __restrict__ bucket, int* __restrict__ cnt, int n)
{
    int j   = threadIdx.x >> 4;          // token-in-block 0..15
    int l   = threadIdx.x & 15;          // expert
    int tok = blockIdx.x * 16 + j;
    if (tok >= n) return;

    const double* p = lgp + (size_t)tok * (DSPL * EE) + l;
    double s = 0.0;
#pragma unroll
    for (int ds = 0; ds < DSPL; ++ds) s += p[ds * EE];   // coalesced across l

    // top-1
    double m1 = s; int i1 = l;
#pragma unroll
    for (int off = 8; off; off >>= 1) {
        double om = __shfl_xor(m1, off, 16);
        int    oi = __shfl_xor(i1, off, 16);
        if (om > m1 || (om == m1 && oi < i1)) { m1 = om; i1 = oi; }
    }
    // top-2 (mask winner)
    double s2 = (l == i1) ? -1.0e300 : s;
    double m2 = s2; int i2 = l;
#pragma unroll
    for (int off = 8; off; off >>= 1) {
        double om = __shfl_xor(m2, off, 16);
        int    oi = __shfl_xor(i2, off, 16);
        if (om > m2 || (om == m2 && oi < i2)) { m2 = om; i2 = oi; }
    }
    if (l == 0) {
        // w0 = 2*p0/(p0+p1) = 2/(1+exp(l1-l0)); softmax Z cancels; eps below ulp.
        double ed = exp(m2 - m1);             // <= 1
        double w0 = 2.0 / (1.0 + ed);         // scale = ALPHA/R = 2
        Route rt;
        rt.i0 = i1; rt.i1 = i2;
        rt.w0 = (float)w0;
        rt.w1 = (float)(2.0 - w0);
        route[tok] = rt;
        int p0 = atomicAdd(&cnt[i1], 1);
        bucket[(size_t)i1 * n + p0] = (unsigned short)(tok * 2);
        int p1 = atomicAdd(&cnt[i2], 1);
        bucket[(size_t)i2 * n + p1] = (unsigned short)(tok * 2 + 1);
    }
}

// ---------------- K2: A-side, barrier-free main loop, 4 blocks/CU ----------
__device__ __forceinline__ void loadh(float (&hv)[4][TW],
        const float* const (&hp)[TW], int d0) {
#pragma unroll
    for (int dd = 0; dd < 4; ++dd)
#pragma unroll
        for (int ti = 0; ti < TW; ++ti)
            hv[dd][ti] = hp[ti][d0 + dd * 16];
}

__device__ __forceinline__ void computeh(float (&accq)[TW][4], float (&accv)[TW][4],
        const float (&hv)[4][TW], const float* aq, const float* av,
        int d0, int s, int rp) {
#pragma unroll
    for (int dd = 0; dd < 4; ++dd) {
        int d = d0 + dd * 16 + s;
        float4 aqv = *(const float4*)&aq[apos(d, rp)];
        float4 avv = *(const float4*)&av[apos(d, rp)];
        const float* ap = &aqv.x;
        const float* vp = &avv.x;
#pragma unroll
        for (int ti = 0; ti < TW; ++ti) {
            float hvv = hv[dd][ti];
#pragma unroll
            for (int ri = 0; ri < 4; ++ri) {
                accq[ti][ri] = fmaf(hvv, ap[ri], accq[ti][ri]);
                accv[ti][ri] = fmaf(hvv, vp[ri], accv[ti][ri]);
            }
        }
    }
}

// grid (EE, ABLK, DSPLIT) = 1024 blocks, 4/CU (32 KB LDS, round-5 was 2/CU
// at 80 KB -> the 85% latency stall). A-panels staged ONCE per block (single
// barrier, XOR-swizzled dense layout -> 2-way banks); each wave then runs
// independently: TW=4 tokens' h read direct global->VGPR (lanes 0-15 = 64
// contiguous B, rank-quads dup-merged), 2-deep d-chunk pipeline, no barriers
// in the loop. ~100 VGPR -> no scratch (round-4 lesson).
__global__ __launch_bounds__(256, 4) void a_kernel(
    const float* __restrict__ h, const Route* __restrict__ route,
    const unsigned short* __restrict__ bucket, const int* __restrict__ cnt,
    const float* __restrict__ qa, const float* __restrict__ va,
    float* __restrict__ low, int n)
{
    int e  = blockIdx.x;
    int ds = blockIdx.z;
    int cnt_e = cnt[e];
    if ((int)(blockIdx.y * TBI) >= cnt_e) return;   // uniform, before barrier

    __align__(16) __shared__ float aq_s[DRANGE * RR];   // 16 KB, swizzled
    __align__(16) __shared__ float av_s[DRANGE * RR];   // 16 KB, swizzled

    const int dbase = ds * DRANGE;
    const float* qa_e = qa + ((size_t)e * DD + dbase) * RR;
    const float* va_e = va + ((size_t)e * DD + dbase) * RR;

    // stage A panels into swizzled quads: DRANGE*RR/4 = 1024 tasks, 4/thread
    for (int i = threadIdx.x; i < DRANGE * RR / 4; i += 256) {
        int d = i >> 2, rq = i & 3;
        int dst = apos(d, rq);
        *(float4*)&aq_s[dst] = *(const float4*)&qa_e[(size_t)i * 4];
        *(float4*)&av_s[dst] = *(const float4*)&va_e[(size_t)i * 4];
    }
    __syncthreads();   // the ONLY block-wide barrier

    int lane = threadIdx.x & 63;
    int w    = threadIdx.x >> 6;         // wave 0..3
    int s    = lane & 15;                // d-slice
    int rp   = lane >> 4;                // rank quad 0..3

    for (int cb = blockIdx.y * TBI; cb < cnt_e; cb += gridDim.y * TBI) {
        int cw = cb + w * TW;            // this wave's 4 tokens
        if (cw >= cnt_e) continue;       // wave-uniform, no barriers inside

        // lanes 0..3 fetch slot + weight, broadcast via shfl
        int sl = 0; float wt = 0.f;
        if (lane < TW && cw + lane < cnt_e) {
            sl = bucket[(size_t)e * n + cw + lane];
            Route rt = route[sl >> 1];
            wt = (sl & 1) ? rt.w1 : rt.w0;
        }
        const float* hp[TW];
        int   slots[TW];
        float wts[TW];
#pragma unroll
        for (int ti = 0; ti < TW; ++ti) {
            slots[ti] = __shfl(sl, ti);
            wts[ti]   = __shfl(wt, ti);
            hp[ti]    = h + (size_t)(slots[ti] >> 1) * DD + dbase + s;
        }

        float accq[TW][4], accv[TW][4];
#pragma unroll
        for (int ti = 0; ti < TW; ++ti)
#pragma unroll
            for (int ri = 0; ri < 4; ++ri) { accq[ti][ri] = 0.f; accv[ti][ri] = 0.f; }

        float hvA[4][TW], hvB[4][TW];
        loadh(hvA, hp, 0);
#pragma unroll
        for (int d0 = 0; d0 < DRANGE; d0 += 2 * DC) {   // 2 passes
            loadh(hvB, hp, d0 + DC);
            computeh(accq, accv, hvA, aq_s, av_s, d0, s, rp);
            if (d0 + 2 * DC < DRANGE) loadh(hvA, hp, d0 + 2 * DC);
            computeh(accq, accv, hvB, aq_s, av_s, d0 + DC, s, rp);
        }

#pragma unroll
        for (int ti = 0; ti < TW; ++ti)
#pragma unroll
            for (int ri = 0; ri < 4; ++ri) {
#pragma unroll
                for (int off = 8; off; off >>= 1) {
                    accq[ti][ri] += __shfl_down(accq[ti][ri], off, 16);
                    accv[ti][ri] += __shfl_down(accv[ti][ri], off, 16);
                }
            }
        if (s == 0) {
#pragma unroll
            for (int ti = 0; ti < TW; ++ti) {
                if (cw + ti < cnt_e) {
                    int   sl2 = slots[ti];       // tok*2+k
                    float wt2 = wts[ti];
                    size_t base = ((size_t)sl2 * DSPLIT + ds) * 32;
                    float4 q4 = make_float4(accq[ti][0] * wt2, accq[ti][1] * wt2,
                                            accq[ti][2] * wt2, accq[ti][3] * wt2);
                    float4 v4 = make_float4(accv[ti][0] * wt2, accv[ti][1] * wt2,
                                            accv[ti][2] * wt2, accv[ti][3] * wt2);
                    *(float4*)&low[base + rp * 4]      = q4;
                    *(float4*)&low[base + 16 + rp * 4] = v4;
                }
            }
        }
    }
}

// ---------------- K3: B-side, token-major, expert-bucketed ----------------
__global__ __launch_bounds__(256) void b_kernel(
    const Route* __restrict__ route, const float* __restrict__ low,
    const float* __restrict__ qb, const float* __restrict__ vb,
    float* __restrict__ outq, float* __restrict__ outv, int n)
{
    int t0 = blockIdx.x * T2;
    int cg = blockIdx.y;               // 0..7 -> q cols, 8..9 -> v cols
    int tid = threadIdx.x;

    __shared__ float acc_s[T2 * 256];  // 32 KB, [token][col-thread]
    __shared__ float ls[T2 * 2 * RR];  // 4 KB, slot-major low vectors
    __shared__ int   elist[EE * T2];   // 2 KB
    __shared__ int   ecnt[EE];
    __shared__ Route rts[T2];

    if (tid < EE) ecnt[tid] = 0;
    if (tid < T2) {
        int tok = t0 + tid;
        if (tok < n) rts[tid] = route[tok];
        else { rts[tid].i0 = -1; rts[tid].i1 = -1; rts[tid].w0 = 0.f; rts[tid].w1 = 0.f; }
    }
    __syncthreads();
    if (tid < T2 * 2) {
        int j = tid >> 1, k = tid & 1;
        int e = k ? rts[j].i1 : rts[j].i0;
        if (e >= 0) {
            int p = atomicAdd(&ecnt[e], 1);
            elist[e * T2 + p] = j * 2 + k;
        }
    }
    int side = (cg >= CGQ) ? 1 : 0;
    {   // stage ls: 64 slots x 4 float4 groups == 256 tasks == 1/thread
        int slot = tid >> 2, r4 = (tid & 3) * 4;
        int j = slot >> 1, k = slot & 1;
        int tok = t0 + j;
        float4 v = make_float4(0.f, 0.f, 0.f, 0.f);
        if (tok < n) {
            const float* lp = low + (size_t)(tok * 2 + k) * (DSPLIT * 32) + side * 16 + r4;
            float4 acc4 = make_float4(0.f, 0.f, 0.f, 0.f);
#pragma unroll
            for (int dsp = 0; dsp < DSPLIT; ++dsp) {
                float4 p = *(const float4*)(lp + dsp * 32);
                acc4.x += p.x; acc4.y += p.y; acc4.z += p.z; acc4.w += p.w;
            }
            v = acc4;
        }
        *(float4*)&ls[slot * RR + r4] = v;
    }
#pragma unroll
    for (int j = 0; j < T2; ++j) acc_s[j * 256 + tid] = 0.f;
    __syncthreads();

    const float* bp; float* outp; int W, colbase;
    if (cg < CGQ) { bp = qb; outp = outq; W = QO; colbase = cg * 256; }
    else          { bp = vb; outp = outv; W = VO; colbase = (cg - CGQ) * 256; }
    int col = colbase + tid;

    float bcA[RR], bcB[RR];
    {
        const float* be = bp + col;   // expert 0
#pragma unroll
        for (int r = 0; r < RR; ++r) bcA[r] = be[(size_t)r * W];
    }

#define PROC_E(EI, BC)                                                      \
    {                                                                       \
        int c = ecnt[EI];                                                   \
        for (int ii = 0; ii < c; ++ii) {                                    \
            int sk = elist[(EI) * T2 + ii];                                 \
            const float* lp = &ls[sk * RR];                                 \
            float4 l0 = *(const float4*)(lp);                               \
            float4 l1 = *(const float4*)(lp + 4);                           \
            float4 l2 = *(const float4*)(lp + 8);                           \
            float4 l3 = *(const float4*)(lp + 12);                          \
            float v = 0.f;                                                  \
            v = fmaf(l0.x, BC[0],  v); v = fmaf(l0.y, BC[1],  v);           \
            v = fmaf(l0.z, BC[2],  v); v = fmaf(l0.w, BC[3],  v);           \
            v = fmaf(l1.x, BC[4],  v); v = fmaf(l1.y, BC[5],  v);           \
            v = fmaf(l1.z, BC[6],  v); v = fmaf(l1.w, BC[7],  v);           \
            v = fmaf(l2.x, BC[8],  v); v = fmaf(l2.y, BC[9],  v);           \
            v = fmaf(l2.z, BC[10], v); v = fmaf(l2.w, BC[11], v);           \
            v = fmaf(l3.x, BC[12], v); v = fmaf(l3.y, BC[13], v);           \
            v = fmaf(l3.z, BC[14], v); v = fmaf(l3.w, BC[15], v);           \
            acc_s[(sk >> 1) * 256 + tid] += v;  /* thread-private column */ \
        }                                                                   \
    }

    for (int e = 0; e < EE; e += 2) {
        {   // prefetch odd expert while even computes
            const float* bn = bp + (size_t)(e + 1) * RR * W + col;
#pragma unroll
            for (int r = 0; r < RR; ++r) bcB[r] = bn[(size_t)r * W];
        }
        PROC_E(e, bcA);
        if (e + 2 < EE) {   // prefetch next even expert
            const float* bn = bp + (size_t)(e + 2) * RR * W + col;
#pragma unroll
            for (int r = 0; r < RR; ++r) bcA[r] = bn[(size_t)r * W];
        }
        PROC_E(e + 1, bcB);
    }
#undef PROC_E

    // each thread wrote only its own acc column -> no barrier needed
#pragma unroll
    for (int j = 0; j < T2; ++j) {
        int tok = t0 + j;
        if (tok < n) outp[(size_t)tok * W + col] = acc_s[j * 256 + tid];
    }
}

extern "C" void kernel_launch(void* const* d_in, const int* in_sizes, int n_in,
                              void* d_out, int out_size, void* d_ws, size_t ws_size,
                              hipStream_t stream) {
    const float* h  = (const float*)d_in[0];
    const float* rw = (const float*)d_in[1];
    const float* qa = (const float*)d_in[2];
    const float* qb = (const float*)d_in[3];
    const float* va = (const float*)d_in[4];
    const float* vb = (const float*)d_in[5];

    int n = in_sizes[0] / DD;
    float* out  = (float*)d_out;
    float* outq = out;
    float* outv = out + (size_t)n * QO;

    char* ws = (char*)d_ws;
    Route* route = (Route*)ws;                                     // n*16 B
    size_t off = ((size_t)n * sizeof(Route) + 255) & ~(size_t)255;
    int* cnt = (int*)(ws + off);                                   // EE ints
    off = (off + EE * sizeof(int) + 255) & ~(size_t)255;
    unsigned short* bucket = (unsigned short*)(ws + off);          // EE*n*2 B
    off = (off + (size_t)EE * n * sizeof(unsigned short) + 255) & ~(size_t)255;
    float* low = (float*)(ws + off);   // n*2*DSPLIT*32 floats = n*2048 B (8 MB)
    // lgp ALIASES low: lgp (n*DSPL*EE*8 = n*1024 B) is fully consumed by
    // finalize_kernel before a_kernel writes low -> zero extra ws footprint.
    double* lgp = (double*)low;

    dim3 g1((n + 7) / 8, DSPL);
    logits_kernel<<<g1, 256, 0, stream>>>(h, rw, lgp, cnt, n);

    finalize_kernel<<<(n + 15) / 16, 256, 0, stream>>>(lgp, route, bucket, cnt, n);

    dim3 g2(EE, ABLK, DSPLIT);
    a_kernel<<<g2, 256, 0, stream>>>(h, route, bucket, cnt, qa, va, low, n);

    dim3 g3((n + T2 - 1) / T2, CGQ + CGV);
    b_kernel<<<g3, 256, 0, stream>>>(route, low, qb, vb, outq, outv, n);
}

// Round 7
// 222.781 us; speedup vs baseline: 1.0116x; 1.0116x over previous
//
#include <hip/hip_runtime.h>
#include <math.h>

#define DD 2048   // hidden dim
#define EE 16     // experts
#define RR 16     // lora rank
#define QO 2048   // q out dim
#define VO 512    // v out dim
#define DSPLIT 8  // D splits for A-side grid (32 KB panels -> 4 blocks/CU)
#define DRANGE (DD / DSPLIT)   // 256
#define DC 64     // D-chunk per pipeline stage
#define RDC 256        // router D-chunk
#define DSPL 8         // router D-split (one RDC chunk per block)
#define TW 4           // tokens per WAVE (live set ~90 VGPR at 128 cap -> no spill)
#define TBI (TW * 4)   // 16 tokens per block iteration (4 waves)
#define ABLK 8         // a_kernel grid.y -> 16*8*8 = 1024 blocks = 4/CU, 1 round
#define T2 32          // B-side tokens per tile
#define CGQ (QO / 256) // 8 q column groups
#define CGV (VO / 256) // 2 v column groups

struct Route { int i0, i1; float w0, w1; };

// XOR-swizzled A-panel addressing (dense [DRANGE][16] + quad swizzle).
// Read lanes (s, rp) at d = s+16k hit bank-quads (s&1)<<2 | (rp^((s>>1)&3))
// -> bijective over s&7 -> 2-way conflict (free), no padding (16 KB/panel).
// Round-6 PMC: SQ_LDS_BANK_CONFLICT == 0 with this layout.
__device__ __forceinline__ int apos(int d, int rq) {
    return d * 16 + ((rq ^ ((d >> 1) & 3)) << 2);
}

// ---------------- K1a: partial fp64 logits over a 256-wide D slice --------
// grid (n/8, DSPL). Block (0,0) also zeroes cnt (consumed only by finalize,
// which is stream-ordered after this kernel).
__global__ __launch_bounds__(256) void logits_kernel(
    const float* __restrict__ h, const float* __restrict__ rw,
    double* __restrict__ lgp, int* __restrict__ cnt, int n)
{
    __shared__ float hs[8 * RDC];       // 8 KB

    if (blockIdx.x == 0 && blockIdx.y == 0 && threadIdx.x < EE)
        cnt[threadIdx.x] = 0;

    int t0 = blockIdx.x * 8;
    int ds = blockIdx.y;
    int d0 = ds * RDC;
    int e  = threadIdx.x >> 4;
    int l  = threadIdx.x & 15;

    // stage h chunk: 8 tokens x 256 d = 512 float4 tasks = 2/thread
    for (int i = threadIdx.x; i < 8 * (RDC / 4); i += 256) {
        int t = i >> 6, dq = (i & 63) * 4;
        float4 v = make_float4(0.f, 0.f, 0.f, 0.f);
        if (t0 + t < n)
            v = *(const float4*)&h[(size_t)(t0 + t) * DD + d0 + dq];
        *(float4*)&hs[t * RDC + dq] = v;
    }
    __syncthreads();

    double acc[8];
#pragma unroll
    for (int t = 0; t < 8; ++t) acc[t] = 0.0;

    const float* rwe = rw + e * DD + d0;
#pragma unroll
    for (int g = 0; g < RDC / 64; ++g) {          // 4 passes
        int d = g * 64 + l * 4;
        float4 r4 = *(const float4*)&rwe[d];
        double rx = r4.x, ry = r4.y, rz = r4.z, rw4 = r4.w;
#pragma unroll
        for (int t = 0; t < 8; ++t) {
            float4 hv = *(const float4*)&hs[t * RDC + d];
            acc[t] += (double)hv.x * rx + (double)hv.y * ry
                    + (double)hv.z * rz + (double)hv.w * rw4;
        }
    }
#pragma unroll
    for (int t = 0; t < 8; ++t) {
#pragma unroll
        for (int off = 8; off; off >>= 1)
            acc[t] += __shfl_down(acc[t], off, 16);
    }
    if (l == 0) {
#pragma unroll
        for (int t = 0; t < 8; ++t) {
            int tok = t0 + t;
            if (tok < n)
                lgp[((size_t)tok * DSPL + ds) * EE + e] = acc[t];
        }
    }
}

// ---------------- K1b: finalize router, 16 lanes per token ----------------
// Lane l = expert. fp64 ds-sum in fixed order (bit-identical to serial).
// Butterfly argmax with lowest-index tie-break == serial scan semantics.
__global__ __launch_bounds__(256) void finalize_kernel(
    const double* __restrict__ lgp, Route* __restrict__ route,
    unsigned short* __restrict__ bucket, int* __restrict__ cnt, int n)
{
    int j   = threadIdx.x >> 4;          // token-in-block 0..15
    int l   = threadIdx.x & 15;          // expert
    int tok = blockIdx.x * 16 + j;
    if (tok >= n) return;

    const double* p = lgp + (size_t)tok * (DSPL * EE) + l;
    double s = 0.0;
#pragma unroll
    for (int ds = 0; ds < DSPL; ++ds) s += p[ds * EE];   // coalesced across l

    // top-1
    double m1 = s; int i1 = l;
#pragma unroll
    for (int off = 8; off; off >>= 1) {
        double om = __shfl_xor(m1, off, 16);
        int    oi = __shfl_xor(i1, off, 16);
        if (om > m1 || (om == m1 && oi < i1)) { m1 = om; i1 = oi; }
    }
    // top-2 (mask winner)
    double s2 = (l == i1) ? -1.0e300 : s;
    double m2 = s2; int i2 = l;
#pragma unroll
    for (int off = 8; off; off >>= 1) {
        double om = __shfl_xor(m2, off, 16);
        int    oi = __shfl_xor(i2, off, 16);
        if (om > m2 || (om == m2 && oi < i2)) { m2 = om; i2 = oi; }
    }
    if (l == 0) {
        // w0 = 2*p0/(p0+p1) = 2/(1+exp(l1-l0)); softmax Z cancels; eps below ulp.
        double ed = exp(m2 - m1);             // <= 1
        double w0 = 2.0 / (1.0 + ed);         // scale = ALPHA/R = 2
        Route rt;
        rt.i0 = i1; rt.i1 = i2;
        rt.w0 = (float)w0;
        rt.w1 = (float)(2.0 - w0);
        route[tok] = rt;
        int p0 = atomicAdd(&cnt[i1], 1);
        bucket[(size_t)i1 * n + p0] = (unsigned short)(tok * 2);
        int p1 = atomicAdd(&cnt[i2], 1);
        bucket[(size_t)i2 * n + p1] = (unsigned short)(tok * 2 + 1);
    }
}

// ---------------- K2: A-side, barrier-free main loop, 4 blocks/CU ----------
__device__ __forceinline__ void loadh(float (&hv)[4][TW],
        const float* const (&hp)[TW], int d0) {
#pragma unroll
    for (int dd = 0; dd < 4; ++dd)
#pragma unroll
        for (int ti = 0; ti < TW; ++ti)
            hv[dd][ti] = hp[ti][d0 + dd * 16];
}

__device__ __forceinline__ void computeh(float (&accq)[TW][4], float (&accv)[TW][4],
        const float (&hv)[4][TW], const float* aq, const float* av,
        int d0, int s, int rp) {
#pragma unroll
    for (int dd = 0; dd < 4; ++dd) {
        int d = d0 + dd * 16 + s;
        float4 aqv = *(const float4*)&aq[apos(d, rp)];
        float4 avv = *(const float4*)&av[apos(d, rp)];
        const float* ap = &aqv.x;
        const float* vp = &avv.x;
#pragma unroll
        for (int ti = 0; ti < TW; ++ti) {
            float hvv = hv[dd][ti];
#pragma unroll
            for (int ri = 0; ri < 4; ++ri) {
                accq[ti][ri] = fmaf(hvv, ap[ri], accq[ti][ri]);
                accv[ti][ri] = fmaf(hvv, vp[ri], accv[ti][ri]);
            }
        }
    }
}

// grid (EE, ABLK, DSPLIT) = 1024 blocks, 4/CU at 32 KB LDS + 128 VGPR.
// __launch_bounds__(256, 2): round-6 lesson — the (256,4) bound made the
// allocator squeeze to 64 VGPR and spill ~25 MB/dispatch (WRITE_SIZE 34 MB
// vs 8.4 legit). (256,2) is proven (round 5) to give 128 VGPR, spill-free;
// occupancy is then VGPR-limited to the SAME 4 blocks/CU we want.
// A-panels staged ONCE per block (single barrier, XOR-swizzled dense layout,
// 0 bank conflicts per round-6 PMC); each wave runs independently: TW=4
// tokens' h read direct global->VGPR (lanes 0-15 = 64 contiguous B), 2-deep
// d-chunk pipeline, no barriers in the loop.
__global__ __launch_bounds__(256, 2) void a_kernel(
    const float* __restrict__ h, const Route* __restrict__ route,
    const unsigned short* __restrict__ bucket, const int* __restrict__ cnt,
    const float* __restrict__ qa, const float* __restrict__ va,
    float* __restrict__ low, int n)
{
    int e  = blockIdx.x;
    int ds = blockIdx.z;
    int cnt_e = cnt[e];
    if ((int)(blockIdx.y * TBI) >= cnt_e) return;   // uniform, before barrier

    __align__(16) __shared__ float aq_s[DRANGE * RR];   // 16 KB, swizzled
    __align__(16) __shared__ float av_s[DRANGE * RR];   // 16 KB, swizzled

    const int dbase = ds * DRANGE;
    const float* qa_e = qa + ((size_t)e * DD + dbase) * RR;
    const float* va_e = va + ((size_t)e * DD + dbase) * RR;

    // stage A panels into swizzled quads: DRANGE*RR/4 = 1024 tasks, 4/thread
    for (int i = threadIdx.x; i < DRANGE * RR / 4; i += 256) {
        int d = i >> 2, rq = i & 3;
        int dst = apos(d, rq);
        *(float4*)&aq_s[dst] = *(const float4*)&qa_e[(size_t)i * 4];
        *(float4*)&av_s[dst] = *(const float4*)&va_e[(size_t)i * 4];
    }
    __syncthreads();   // the ONLY block-wide barrier

    int lane = threadIdx.x & 63;
    int w    = threadIdx.x >> 6;         // wave 0..3
    int s    = lane & 15;                // d-slice
    int rp   = lane >> 4;                // rank quad 0..3

    for (int cb = blockIdx.y * TBI; cb < cnt_e; cb += gridDim.y * TBI) {
        int cw = cb + w * TW;            // this wave's 4 tokens
        if (cw >= cnt_e) continue;       // wave-uniform, no barriers inside

        // lanes 0..3 fetch slot + weight, broadcast via shfl
        int sl = 0; float wt = 0.f;
        if (lane < TW && cw + lane < cnt_e) {
            sl = bucket[(size_t)e * n + cw + lane];
            Route rt = route[sl >> 1];
            wt = (sl & 1) ? rt.w1 : rt.w0;
        }
        const float* hp[TW];
        int   slots[TW];
        float wts[TW];
#pragma unroll
        for (int ti = 0; ti < TW; ++ti) {
            slots[ti] = __shfl(sl, ti);
            wts[ti]   = __shfl(wt, ti);
            hp[ti]    = h + (size_t)(slots[ti] >> 1) * DD + dbase + s;
        }

        float accq[TW][4], accv[TW][4];
#pragma unroll
        for (int ti = 0; ti < TW; ++ti)
#pragma unroll
            for (int ri = 0; ri < 4; ++ri) { accq[ti][ri] = 0.f; accv[ti][ri] = 0.f; }

        float hvA[4][TW], hvB[4][TW];
        loadh(hvA, hp, 0);
#pragma unroll
        for (int d0 = 0; d0 < DRANGE; d0 += 2 * DC) {   // 2 passes
            loadh(hvB, hp, d0 + DC);
            computeh(accq, accv, hvA, aq_s, av_s, d0, s, rp);
            if (d0 + 2 * DC < DRANGE) loadh(hvA, hp, d0 + 2 * DC);
            computeh(accq, accv, hvB, aq_s, av_s, d0 + DC, s, rp);
        }

#pragma unroll
        for (int ti = 0; ti < TW; ++ti)
#pragma unroll
            for (int ri = 0; ri < 4; ++ri) {
#pragma unroll
                for (int off = 8; off; off >>= 1) {
                    accq[ti][ri] += __shfl_down(accq[ti][ri], off, 16);
                    accv[ti][ri] += __shfl_down(accv[ti][ri], off, 16);
                }
            }
        if (s == 0) {
#pragma unroll
            for (int ti = 0; ti < TW; ++ti) {
                if (cw + ti < cnt_e) {
                    int   sl2 = slots[ti];       // tok*2+k
                    float wt2 = wts[ti];
                    size_t base = ((size_t)sl2 * DSPLIT + ds) * 32;
                    float4 q4 = make_float4(accq[ti][0] * wt2, accq[ti][1] * wt2,
                                            accq[ti][2] * wt2, accq[ti][3] * wt2);
                    float4 v4 = make_float4(accv[ti][0] * wt2, accv[ti][1] * wt2,
                                            accv[ti][2] * wt2, accv[ti][3] * wt2);
                    *(float4*)&low[base + rp * 4]      = q4;
                    *(float4*)&low[base + 16 + rp * 4] = v4;
                }
            }
        }
    }
}

// ---------------- K3: B-side, token-major, expert-bucketed ----------------
__global__ __launch_bounds__(256) void b_kernel(
    const Route* __restrict__ route, const float* __restrict__ low,
    const float* __restrict__ qb, const float* __restrict__ vb,
    float* __restrict__ outq, float* __restrict__ outv, int n)
{
    int t0 = blockIdx.x * T2;
    int cg = blockIdx.y;               // 0..7 -> q cols, 8..9 -> v cols
    int tid = threadIdx.x;

    __shared__ float acc_s[T2 * 256];  // 32 KB, [token][col-thread]
    __shared__ float ls[T2 * 2 * RR];  // 4 KB, slot-major low vectors
    __shared__ int   elist[EE * T2];   // 2 KB
    __shared__ int   ecnt[EE];
    __shared__ Route rts[T2];

    if (tid < EE) ecnt[tid] = 0;
    if (tid < T2) {
        int tok = t0 + tid;
        if (tok < n) rts[tid] = route[tok];
        else { rts[tid].i0 = -1; rts[tid].i1 = -1; rts[tid].w0 = 0.f; rts[tid].w1 = 0.f; }
    }
    __syncthreads();
    if (tid < T2 * 2) {
        int j = tid >> 1, k = tid & 1;
        int e = k ? rts[j].i1 : rts[j].i0;
        if (e >= 0) {
            int p = atomicAdd(&ecnt[e], 1);
            elist[e * T2 + p] = j * 2 + k;
        }
    }
    int side = (cg >= CGQ) ? 1 : 0;
    {   // stage ls: 64 slots x 4 float4 groups == 256 tasks == 1/thread
        int slot = tid >> 2, r4 = (tid & 3) * 4;
        int j = slot >> 1, k = slot & 1;
        int tok = t0 + j;
        float4 v = make_float4(0.f, 0.f, 0.f, 0.f);
        if (tok < n) {
            const float* lp = low + (size_t)(tok * 2 + k) * (DSPLIT * 32) + side * 16 + r4;
            float4 acc4 = make_float4(0.f, 0.f, 0.f, 0.f);
#pragma unroll
            for (int dsp = 0; dsp < DSPLIT; ++dsp) {
                float4 p = *(const float4*)(lp + dsp * 32);
                acc4.x += p.x; acc4.y += p.y; acc4.z += p.z; acc4.w += p.w;
            }
            v = acc4;
        }
        *(float4*)&ls[slot * RR + r4] = v;
    }
#pragma unroll
    for (int j = 0; j < T2; ++j) acc_s[j * 256 + tid] = 0.f;
    __syncthreads();

    const float* bp; float* outp; int W, colbase;
    if (cg < CGQ) { bp = qb; outp = outq; W = QO; colbase = cg * 256; }
    else          { bp = vb; outp = outv; W = VO; colbase = (cg - CGQ) * 256; }
    int col = colbase + tid;

    float bcA[RR], bcB[RR];
    {
        const float* be = bp + col;   // expert 0
#pragma unroll
        for (int r = 0; r < RR; ++r) bcA[r] = be[(size_t)r * W];
    }

#define PROC_E(EI, BC)                                                      \
    {                                                                       \
        int c = ecnt[EI];                                                   \
        for (int ii = 0; ii < c; ++ii) {                                    \
            int sk = elist[(EI) * T2 + ii];                                 \
            const float* lp = &ls[sk * RR];                                 \
            float4 l0 = *(const float4*)(lp);                               \
            float4 l1 = *(const float4*)(lp + 4);                           \
            float4 l2 = *(const float4*)(lp + 8);                           \
            float4 l3 = *(const float4*)(lp + 12);                          \
            float v = 0.f;                                                  \
            v = fmaf(l0.x, BC[0],  v); v = fmaf(l0.y, BC[1],  v);           \
            v = fmaf(l0.z, BC[2],  v); v = fmaf(l0.w, BC[3],  v);           \
            v = fmaf(l1.x, BC[4],  v); v = fmaf(l1.y, BC[5],  v);           \
            v = fmaf(l1.z, BC[6],  v); v = fmaf(l1.w, BC[7],  v);           \
            v = fmaf(l2.x, BC[8],  v); v = fmaf(l2.y, BC[9],  v);           \
            v = fmaf(l2.z, BC[10], v); v = fmaf(l2.w, BC[11], v);           \
            v = fmaf(l3.x, BC[12], v); v = fmaf(l3.y, BC[13], v);           \
            v = fmaf(l3.z, BC[14], v); v = fmaf(l3.w, BC[15], v);           \
            acc_s[(sk >> 1) * 256 + tid] += v;  /* thread-private column */ \
        }                                                                   \
    }

    for (int e = 0; e < EE; e += 2) {
        {   // prefetch odd expert while even computes
            const float* bn = bp + (size_t)(e + 1) * RR * W + col;
#pragma unroll
            for (int r = 0; r < RR; ++r) bcB[r] = bn[(size_t)r * W];
        }
        PROC_E(e, bcA);
        if (e + 2 < EE) {   // prefetch next even expert
            const float* bn = bp + (size_t)(e + 2) * RR * W + col;
#pragma unroll
            for (int r = 0; r < RR; ++r) bcA[r] = bn[(size_t)r * W];
        }
        PROC_E(e + 1, bcB);
    }
#undef PROC_E

    // each thread wrote only its own acc column -> no barrier needed
#pragma unroll
    for (int j = 0; j < T2; ++j) {
        int tok = t0 + j;
        if (tok < n) outp[(size_t)tok * W + col] = acc_s[j * 256 + tid];
    }
}

extern "C" void kernel_launch(void* const* d_in, const int* in_sizes, int n_in,
                              void* d_out, int out_size, void* d_ws, size_t ws_size,
                              hipStream_t stream) {
    const float* h  = (const float*)d_in[0];
    const float* rw = (const float*)d_in[1];
    const float* qa = (const float*)d_in[2];
    const float* qb = (const float*)d_in[3];
    const float* va = (const float*)d_in[4];
    const float* vb = (const float*)d_in[5];

    int n = in_sizes[0] / DD;
    float* out  = (float*)d_out;
    float* outq = out;
    float* outv = out + (size_t)n * QO;

    char* ws = (char*)d_ws;
    Route* route = (Route*)ws;                                     // n*16 B
    size_t off = ((size_t)n * sizeof(Route) + 255) & ~(size_t)255;
    int* cnt = (int*)(ws + off);                                   // EE ints
    off = (off + EE * sizeof(int) + 255) & ~(size_t)255;
    unsigned short* bucket = (unsigned short*)(ws + off);          // EE*n*2 B
    off = (off + (size_t)EE * n * sizeof(unsigned short) + 255) & ~(size_t)255;
    float* low = (float*)(ws + off);   // n*2*DSPLIT*32 floats = n*2048 B (8 MB)
    // lgp ALIASES low: lgp (n*DSPL*EE*8 = n*1024 B) is fully consumed by
    // finalize_kernel before a_kernel writes low -> zero extra ws footprint.
    double* lgp = (double*)low;

    dim3 g1((n + 7) / 8, DSPL);
    logits_kernel<<<g1, 256, 0, stream>>>(h, rw, lgp, cnt, n);

    finalize_kernel<<<(n + 15) / 16, 256, 0, stream>>>(lgp, route, bucket, cnt, n);

    dim3 g2(EE, ABLK, DSPLIT);
    a_kernel<<<g2, 256, 0, stream>>>(h, route, bucket, cnt, qa, va, low, n);

    dim3 g3((n + T2 - 1) / T2, CGQ + CGV);
    b_kernel<<<g3, 256, 0, stream>>>(route, low, qb, vb, outq, outv, n);
}

// Round 9
// 204.561 us; speedup vs baseline: 1.1016x; 1.0891x over previous
//
#include <hip/hip_runtime.h>
#include <math.h>

#define DD 2048   // hidden dim
#define EE 16     // experts
#define RR 16     // lora rank
#define QO 2048   // q out dim
#define VO 512    // v out dim
#define DSPLIT 8  // D splits for A-side grid (32 KB panels -> 4 blocks/CU)
#define DRANGE (DD / DSPLIT)   // 256
#define DC 64     // D-chunk per pipeline stage
#define RDC 256        // router D-chunk
#define DSPL 8         // router D-split (one RDC chunk per block)
#define TW 4           // tokens per WAVE (live set fits 72 VGPR -> no spill, round 7)
#define TBI (TW * 4)   // 16 tokens per block iteration (4 waves)
#define ABLK 8         // a_kernel grid.y -> 16*8*8 = 1024 blocks = 4/CU, 1 round
#define T2 32          // B-side tokens per tile
#define CGQ (QO / 256) // 8 q column groups
#define CGV (VO / 256) // 2 v column groups

struct Route { int i0, i1; float w0, w1; };

// ---- DPP row-reduction: shfl_down(x,N,16) === v_mov_b32_dpp ROW_SHL:N ----
// ROUND-8 BUG: row_shr:N (0x11N) moves lane i-N -> i (sum accumulates UP,
// total in lane 15; AMD's canonical DPP reduce ends in the LAST lane).
// shfl_down needs lane i+N -> i, i.e. row_shl:N (0x10N). With bound_ctrl=1
// (zero-fill past row edge) this is the exact mirror: identical pairwise
// tree, identical addend order at lane 0 -> BIT-IDENTICAL to shfl_down.
// Still VALU instead of ds_bpermute: round-7 pipe model showed the 2.1M-
// bpermute reduction tail was ~20 us of a_kernel's 51 us LDS-pipe load.
#define DPPF(x, CTRL) __int_as_float(__builtin_amdgcn_update_dpp( \
        0, __float_as_int(x), (CTRL), 0xF, 0xF, true))
__device__ __forceinline__ float rowsum16(float x) {
    x += DPPF(x, 0x108);   // row_shl:8  (lane i += lane i+8)
    x += DPPF(x, 0x104);   // row_shl:4
    x += DPPF(x, 0x102);   // row_shl:2
    x += DPPF(x, 0x101);   // row_shl:1
    return x;              // lane s=0 of each row holds the row sum
}
#define DPPD_STEP(x, CTRL)                                                  \
    {                                                                       \
        int lo_ = __builtin_amdgcn_update_dpp(0, __double2loint(x), (CTRL), \
                                              0xF, 0xF, true);              \
        int hi_ = __builtin_amdgcn_update_dpp(0, __double2hiint(x), (CTRL), \
                                              0xF, 0xF, true);              \
        (x) += __hiloint2double(hi_, lo_);                                  \
    }
__device__ __forceinline__ double rowsum16d(double x) {
    DPPD_STEP(x, 0x108);   // row_shl:8
    DPPD_STEP(x, 0x104);   // row_shl:4
    DPPD_STEP(x, 0x102);   // row_shl:2
    DPPD_STEP(x, 0x101);   // row_shl:1
    return x;              // lane l=0 holds the sum
}

// XOR-swizzled A-panel addressing (dense [DRANGE][16] + quad swizzle).
// Round-6/7 PMC: SQ_LDS_BANK_CONFLICT == 0 with this layout.
__device__ __forceinline__ int apos(int d, int rq) {
    return d * 16 + ((rq ^ ((d >> 1) & 3)) << 2);
}

// ---------------- K1a: partial fp64 logits over a 256-wide D slice --------
// grid (n/8, DSPL). Block (0,0) also zeroes cnt (consumed only by finalize,
// which is stream-ordered after this kernel).
__global__ __launch_bounds__(256) void logits_kernel(
    const float* __restrict__ h, const float* __restrict__ rw,
    double* __restrict__ lgp, int* __restrict__ cnt, int n)
{
    __shared__ float hs[8 * RDC];       // 8 KB

    if (blockIdx.x == 0 && blockIdx.y == 0 && threadIdx.x < EE)
        cnt[threadIdx.x] = 0;

    int t0 = blockIdx.x * 8;
    int ds = blockIdx.y;
    int d0 = ds * RDC;
    int e  = threadIdx.x >> 4;
    int l  = threadIdx.x & 15;

    // stage h chunk: 8 tokens x 256 d = 512 float4 tasks = 2/thread
    for (int i = threadIdx.x; i < 8 * (RDC / 4); i += 256) {
        int t = i >> 6, dq = (i & 63) * 4;
        float4 v = make_float4(0.f, 0.f, 0.f, 0.f);
        if (t0 + t < n)
            v = *(const float4*)&h[(size_t)(t0 + t) * DD + d0 + dq];
        *(float4*)&hs[t * RDC + dq] = v;
    }
    __syncthreads();

    double acc[8];
#pragma unroll
    for (int t = 0; t < 8; ++t) acc[t] = 0.0;

    const float* rwe = rw + e * DD + d0;
#pragma unroll
    for (int g = 0; g < RDC / 64; ++g) {          // 4 passes
        int d = g * 64 + l * 4;
        float4 r4 = *(const float4*)&rwe[d];
        double rx = r4.x, ry = r4.y, rz = r4.z, rw4 = r4.w;
#pragma unroll
        for (int t = 0; t < 8; ++t) {
            float4 hv = *(const float4*)&hs[t * RDC + d];
            acc[t] += (double)hv.x * rx + (double)hv.y * ry
                    + (double)hv.z * rz + (double)hv.w * rw4;
        }
    }
#pragma unroll
    for (int t = 0; t < 8; ++t) acc[t] = rowsum16d(acc[t]);
    if (l == 0) {
#pragma unroll
        for (int t = 0; t < 8; ++t) {
            int tok = t0 + t;
            if (tok < n)
                lgp[((size_t)tok * DSPL + ds) * EE + e] = acc[t];
        }
    }
}

// ---------------- K1b: finalize router, 16 lanes per token ----------------
// Lane l = expert. fp64 ds-sum in fixed order (bit-identical to serial).
// Butterfly argmax with lowest-index tie-break == serial scan semantics.
__global__ __launch_bounds__(256) void finalize_kernel(
    const double* __restrict__ lgp, Route* __restrict__ route,
    unsigned short* __restrict__ bucket, int* __restrict__ cnt, int n)
{
    int j   = threadIdx.x >> 4;          // token-in-block 0..15
    int l   = threadIdx.x & 15;          // expert
    int tok = blockIdx.x * 16 + j;
    if (tok >= n) return;

    const double* p = lgp + (size_t)tok * (DSPL * EE) + l;
    double s = 0.0;
#pragma unroll
    for (int ds = 0; ds < DSPL; ++ds) s += p[ds * EE];   // coalesced across l

    // top-1
    double m1 = s; int i1 = l;
#pragma unroll
    for (int off = 8; off; off >>= 1) {
        double om = __shfl_xor(m1, off, 16);
        int    oi = __shfl_xor(i1, off, 16);
        if (om > m1 || (om == m1 && oi < i1)) { m1 = om; i1 = oi; }
    }
    // top-2 (mask winner)
    double s2 = (l == i1) ? -1.0e300 : s;
    double m2 = s2; int i2 = l;
#pragma unroll
    for (int off = 8; off; off >>= 1) {
        double om = __shfl_xor(m2, off, 16);
        int    oi = __shfl_xor(i2, off, 16);
        if (om > m2 || (om == m2 && oi < i2)) { m2 = om; i2 = oi; }
    }
    if (l == 0) {
        // w0 = 2*p0/(p0+p1) = 2/(1+exp(l1-l0)); softmax Z cancels; eps below ulp.
        double ed = exp(m2 - m1);             // <= 1
        double w0 = 2.0 / (1.0 + ed);         // scale = ALPHA/R = 2
        Route rt;
        rt.i0 = i1; rt.i1 = i2;
        rt.w0 = (float)w0;
        rt.w1 = (float)(2.0 - w0);
        route[tok] = rt;
        int p0 = atomicAdd(&cnt[i1], 1);
        bucket[(size_t)i1 * n + p0] = (unsigned short)(tok * 2);
        int p1 = atomicAdd(&cnt[i2], 1);
        bucket[(size_t)i2 * n + p1] = (unsigned short)(tok * 2 + 1);
    }
}

// ---------------- K2: A-side, barrier-free main loop, 4 blocks/CU ----------
__device__ __forceinline__ void loadh(float (&hv)[4][TW],
        const float* const (&hp)[TW], int d0) {
#pragma unroll
    for (int dd = 0; dd < 4; ++dd)
#pragma unroll
        for (int ti = 0; ti < TW; ++ti)
            hv[dd][ti] = hp[ti][d0 + dd * 16];
}

__device__ __forceinline__ void computeh(float (&accq)[TW][4], float (&accv)[TW][4],
        const float (&hv)[4][TW], const float* aq, const float* av,
        int d0, int s, int rp) {
#pragma unroll
    for (int dd = 0; dd < 4; ++dd) {
        int d = d0 + dd * 16 + s;
        float4 aqv = *(const float4*)&aq[apos(d, rp)];
        float4 avv = *(const float4*)&av[apos(d, rp)];
        const float* ap = &aqv.x;
        const float* vp = &avv.x;
#pragma unroll
        for (int ti = 0; ti < TW; ++ti) {
            float hvv = hv[dd][ti];
#pragma unroll
            for (int ri = 0; ri < 4; ++ri) {
                accq[ti][ri] = fmaf(hvv, ap[ri], accq[ti][ri]);
                accv[ti][ri] = fmaf(hvv, vp[ri], accv[ti][ri]);
            }
        }
    }
}

// grid (EE, ABLK, DSPLIT) = 1024 blocks, 4/CU at 32 KB LDS, 72 VGPR (round 7,
// spill-free with __launch_bounds__(256,2); (256,4) squeezed to 64 and
// spilled — round-6 lesson). A-panels staged ONCE per block (single barrier,
// XOR-swizzled, 0 bank conflicts); each wave independent: TW=4 tokens' h read
// direct global->VGPR, 2-deep d-chunk pipeline, no barriers in the loop.
// Reduction tail on DPP row_shl (VALU) instead of ds_bpermute (LDS pipe).
__global__ __launch_bounds__(256, 2) void a_kernel(
    const float* __restrict__ h, const Route* __restrict__ route,
    const unsigned short* __restrict__ bucket, const int* __restrict__ cnt,
    const float* __restrict__ qa, const float* __restrict__ va,
    float* __restrict__ low, int n)
{
    int e  = blockIdx.x;
    int ds = blockIdx.z;
    int cnt_e = cnt[e];
    if ((int)(blockIdx.y * TBI) >= cnt_e) return;   // uniform, before barrier

    __align__(16) __shared__ float aq_s[DRANGE * RR];   // 16 KB, swizzled
    __align__(16) __shared__ float av_s[DRANGE * RR];   // 16 KB, swizzled

    const int dbase = ds * DRANGE;
    const float* qa_e = qa + ((size_t)e * DD + dbase) * RR;
    const float* va_e = va + ((size_t)e * DD + dbase) * RR;

    // stage A panels into swizzled quads: DRANGE*RR/4 = 1024 tasks, 4/thread
    for (int i = threadIdx.x; i < DRANGE * RR / 4; i += 256) {
        int d = i >> 2, rq = i & 3;
        int dst = apos(d, rq);
        *(float4*)&aq_s[dst] = *(const float4*)&qa_e[(size_t)i * 4];
        *(float4*)&av_s[dst] = *(const float4*)&va_e[(size_t)i * 4];
    }
    __syncthreads();   // the ONLY block-wide barrier

    int lane = threadIdx.x & 63;
    int w    = threadIdx.x >> 6;         // wave 0..3
    int s    = lane & 15;                // d-slice
    int rp   = lane >> 4;                // rank quad 0..3

    for (int cb = blockIdx.y * TBI; cb < cnt_e; cb += gridDim.y * TBI) {
        int cw = cb + w * TW;            // this wave's 4 tokens
        if (cw >= cnt_e) continue;       // wave-uniform, no barriers inside

        // lanes 0..3 fetch slot + weight, broadcast via shfl
        int sl = 0; float wt = 0.f;
        if (lane < TW && cw + lane < cnt_e) {
            sl = bucket[(size_t)e * n + cw + lane];
            Route rt = route[sl >> 1];
            wt = (sl & 1) ? rt.w1 : rt.w0;
        }
        const float* hp[TW];
        int   slots[TW];
        float wts[TW];
#pragma unroll
        for (int ti = 0; ti < TW; ++ti) {
            slots[ti] = __shfl(sl, ti);
            wts[ti]   = __shfl(wt, ti);
            hp[ti]    = h + (size_t)(slots[ti] >> 1) * DD + dbase + s;
        }

        float accq[TW][4], accv[TW][4];
#pragma unroll
        for (int ti = 0; ti < TW; ++ti)
#pragma unroll
            for (int ri = 0; ri < 4; ++ri) { accq[ti][ri] = 0.f; accv[ti][ri] = 0.f; }

        float hvA[4][TW], hvB[4][TW];
        loadh(hvA, hp, 0);
#pragma unroll
        for (int d0 = 0; d0 < DRANGE; d0 += 2 * DC) {   // 2 passes
            loadh(hvB, hp, d0 + DC);
            computeh(accq, accv, hvA, aq_s, av_s, d0, s, rp);
            if (d0 + 2 * DC < DRANGE) loadh(hvA, hp, d0 + 2 * DC);
            computeh(accq, accv, hvB, aq_s, av_s, d0 + DC, s, rp);
        }

        // DPP row-sum (VALU) — bit-identical tree to the old shfl_down
#pragma unroll
        for (int ti = 0; ti < TW; ++ti)
#pragma unroll
            for (int ri = 0; ri < 4; ++ri) {
                accq[ti][ri] = rowsum16(accq[ti][ri]);
                accv[ti][ri] = rowsum16(accv[ti][ri]);
            }
        if (s == 0) {
#pragma unroll
            for (int ti = 0; ti < TW; ++ti) {
                if (cw + ti < cnt_e) {
                    int   sl2 = slots[ti];       // tok*2+k
                    float wt2 = wts[ti];
                    size_t base = ((size_t)sl2 * DSPLIT + ds) * 32;
                    float4 q4 = make_float4(accq[ti][0] * wt2, accq[ti][1] * wt2,
                                            accq[ti][2] * wt2, accq[ti][3] * wt2);
                    float4 v4 = make_float4(accv[ti][0] * wt2, accv[ti][1] * wt2,
                                            accv[ti][2] * wt2, accv[ti][3] * wt2);
                    *(float4*)&low[base + rp * 4]      = q4;
                    *(float4*)&low[base + 16 + rp * 4] = v4;
                }
            }
        }
    }
}

// ---------------- K3: B-side, token-major, expert-bucketed ----------------
__global__ __launch_bounds__(256) void b_kernel(
    const Route* __restrict__ route, const float* __restrict__ low,
    const float* __restrict__ qb, const float* __restrict__ vb,
    float* __restrict__ outq, float* __restrict__ outv, int n)
{
    int t0 = blockIdx.x * T2;
    int cg = blockIdx.y;               // 0..7 -> q cols, 8..9 -> v cols
    int tid = threadIdx.x;

    __shared__ float acc_s[T2 * 256];  // 32 KB, [token][col-thread]
    __shared__ float ls[T2 * 2 * RR];  // 4 KB, slot-major low vectors
    __shared__ int   elist[EE * T2];   // 2 KB
    __shared__ int   ecnt[EE];
    __shared__ Route rts[T2];

    if (tid < EE) ecnt[tid] = 0;
    if (tid < T2) {
        int tok = t0 + tid;
        if (tok < n) rts[tid] = route[tok];
        else { rts[tid].i0 = -1; rts[tid].i1 = -1; rts[tid].w0 = 0.f; rts[tid].w1 = 0.f; }
    }
    __syncthreads();
    if (tid < T2 * 2) {
        int j = tid >> 1, k = tid & 1;
        int e = k ? rts[j].i1 : rts[j].i0;
        if (e >= 0) {
            int p = atomicAdd(&ecnt[e], 1);
            elist[e * T2 + p] = j * 2 + k;
        }
    }
    int side = (cg >= CGQ) ? 1 : 0;
    {   // stage ls: 64 slots x 4 float4 groups == 256 tasks == 1/thread
        int slot = tid >> 2, r4 = (tid & 3) * 4;
        int j = slot >> 1, k = slot & 1;
        int tok = t0 + j;
        float4 v = make_float4(0.f, 0.f, 0.f, 0.f);
        if (tok < n) {
            const float* lp = low + (size_t)(tok * 2 + k) * (DSPLIT * 32) + side * 16 + r4;
            float4 acc4 = make_float4(0.f, 0.f, 0.f, 0.f);
#pragma unroll
            for (int dsp = 0; dsp < DSPLIT; ++dsp) {
                float4 p = *(const float4*)(lp + dsp * 32);
                acc4.x += p.x; acc4.y += p.y; acc4.z += p.z; acc4.w += p.w;
            }
            v = acc4;
        }
        *(float4*)&ls[slot * RR + r4] = v;
    }
#pragma unroll
    for (int j = 0; j < T2; ++j) acc_s[j * 256 + tid] = 0.f;
    __syncthreads();

    const float* bp; float* outp; int W, colbase;
    if (cg < CGQ) { bp = qb; outp = outq; W = QO; colbase = cg * 256; }
    else          { bp = vb; outp = outv; W = VO; colbase = (cg - CGQ) * 256; }
    int col = colbase + tid;

    float bcA[RR], bcB[RR];
    {
        const float* be = bp + col;   // expert 0
#pragma unroll
        for (int r = 0; r < RR; ++r) bcA[r] = be[(size_t)r * W];
    }

#define PROC_E(EI, BC)                                                      \
    {                                                                       \
        int c = ecnt[EI];                                                   \
        for (int ii = 0; ii < c; ++ii) {                                    \
            int sk = elist[(EI) * T2 + ii];                                 \
            const float* lp = &ls[sk * RR];                                 \
            float4 l0 = *(const float4*)(lp);                               \
            float4 l1 = *(const float4*)(lp + 4);                           \
            float4 l2 = *(const float4*)(lp + 8);                           \
            float4 l3 = *(const float4*)(lp + 12);                          \
            float v = 0.f;                                                  \
            v = fmaf(l0.x, BC[0],  v); v = fmaf(l0.y, BC[1],  v);           \
            v = fmaf(l0.z, BC[2],  v); v = fmaf(l0.w, BC[3],  v);           \
            v = fmaf(l1.x, BC[4],  v); v = fmaf(l1.y, BC[5],  v);           \
            v = fmaf(l1.z, BC[6],  v); v = fmaf(l1.w, BC[7],  v);           \
            v = fmaf(l2.x, BC[8],  v); v = fmaf(l2.y, BC[9],  v);           \
            v = fmaf(l2.z, BC[10], v); v = fmaf(l2.w, BC[11], v);           \
            v = fmaf(l3.x, BC[12], v); v = fmaf(l3.y, BC[13], v);           \
            v = fmaf(l3.z, BC[14], v); v = fmaf(l3.w, BC[15], v);           \
            acc_s[(sk >> 1) * 256 + tid] += v;  /* thread-private column */ \
        }                                                                   \
    }

    for (int e = 0; e < EE; e += 2) {
        {   // prefetch odd expert while even computes
            const float* bn = bp + (size_t)(e + 1) * RR * W + col;
#pragma unroll
            for (int r = 0; r < RR; ++r) bcB[r] = bn[(size_t)r * W];
        }
        PROC_E(e, bcA);
        if (e + 2 < EE) {   // prefetch next even expert
            const float* bn = bp + (size_t)(e + 2) * RR * W + col;
#pragma unroll
            for (int r = 0; r < RR; ++r) bcA[r] = bn[(size_t)r * W];
        }
        PROC_E(e + 1, bcB);
    }
#undef PROC_E

    // each thread wrote only its own acc column -> no barrier needed
#pragma unroll
    for (int j = 0; j < T2; ++j) {
        int tok = t0 + j;
        if (tok < n) outp[(size_t)tok * W + col] = acc_s[j * 256 + tid];
    }
}

extern "C" void kernel_launch(void* const* d_in, const int* in_sizes, int n_in,
                              void* d_out, int out_size, void* d_ws, size_t ws_size,
                              hipStream_t stream) {
    const float* h  = (const float*)d_in[0];
    const float* rw = (const float*)d_in[1];
    const float* qa = (const float*)d_in[2];
    const float* qb = (const float*)d_in[3];
    const float* va = (const float*)d_in[4];
    const float* vb = (const float*)d_in[5];

    int n = in_sizes[0] / DD;
    float* out  = (float*)d_out;
    float* outq = out;
    float* outv = out + (size_t)n * QO;

    char* ws = (char*)d_ws;
    Route* route = (Route*)ws;                                     // n*16 B
    size_t off = ((size_t)n * sizeof(Route) + 255) & ~(size_t)255;
    int* cnt = (int*)(ws + off);                                   // EE ints
    off = (off + EE * sizeof(int) + 255) & ~(size_t)255;
    unsigned short* bucket = (unsigned short*)(ws + off);          // EE*n*2 B
    off = (off + (size_t)EE * n * sizeof(unsigned short) + 255) & ~(size_t)255;
    float* low = (float*)(ws + off);   // n*2*DSPLIT*32 floats = n*2048 B (8 MB)
    // lgp ALIASES low: lgp (n*DSPL*EE*8 = n*1024 B) is fully consumed by
    // finalize_kernel before a_kernel writes low -> zero extra ws footprint.
    double* lgp = (double*)low;

    dim3 g1((n + 7) / 8, DSPL);
    logits_kernel<<<g1, 256, 0, stream>>>(h, rw, lgp, cnt, n);

    finalize_kernel<<<(n + 15) / 16, 256, 0, stream>>>(lgp, route, bucket, cnt, n);

    dim3 g2(EE, ABLK, DSPLIT);
    a_kernel<<<g2, 256, 0, stream>>>(h, route, bucket, cnt, qa, va, low, n);

    dim3 g3((n + T2 - 1) / T2, CGQ + CGV);
    b_kernel<<<g3, 256, 0, stream>>>(route, low, qb, vb, outq, outv, n);
}